// Round 1
// baseline (829.690 us; speedup 1.0000x reference)
//
#include <hip/hip_runtime.h>
#include <math.h>

#define Bb 64
#define Tt 512
#define Dd 1536
#define Hh 30
#define NC 128            // packed cols: 120 gates + ax + bx + 6 pad
#define Mm (Bb*Tt)        // 32768 rows
#define KC 32             // K chunk
#define PSTR 132          // padded LDS row stride (floats)

__device__ __forceinline__ float sigmoidf_(float x) {
    return 1.f / (1.f + __expf(-x));
}
__device__ __forceinline__ float tanhf_fast(float x) {
    float e = __expf(2.f * x);
    return 1.f - 2.f / (e + 1.f);
}
__device__ __forceinline__ float softplus_(float x) {
    return fmaxf(x, 0.f) + __logf(1.f + __expf(-fabsf(x)));
}
__device__ __forceinline__ float rl_f(float v, int lane) {
    return __uint_as_float(__builtin_amdgcn_readlane(__float_as_uint(v), lane));
}

// ---------------- kernel 1: pack weights into [K=1536][128] k-major ----------------
__global__ __launch_bounds__(256) void pack_w(const float* __restrict__ Wih,
                                              const float* __restrict__ Wa,
                                              const float* __restrict__ Wb,
                                              float* __restrict__ Wp) {
    int idx = blockIdx.x * 256 + threadIdx.x;      // < 1536*128
    int k = idx >> 7;
    int c = idx & 127;
    float v = 0.f;
    if (c < 120)       v = Wih[c * (Dd + 1) + k];
    else if (c == 120) v = Wa[k];
    else if (c == 121) v = Wb[k];
    Wp[idx] = v;
}

// ---------------- kernel 2: GX[m][c] = X[m,:] @ Wp[:,c] + bias(c) ----------------
__global__ __launch_bounds__(256) void gemm_k(const float* __restrict__ X,
                                              const float* __restrict__ Wp,
                                              const float* __restrict__ bih,
                                              const float* __restrict__ bhh,
                                              const float* __restrict__ ba,
                                              const float* __restrict__ bbp,
                                              float* __restrict__ GX) {
    __shared__ float Xs[KC][PSTR];   // transposed: Xs[k][row]
    __shared__ float Ws[KC][PSTR];   // Ws[k][col]
    const int t = threadIdx.x;
    const int m0 = blockIdx.x * 128;
    const int tc = t & 15;
    const int tr = t >> 4;
    const int c0 = tc * 8;
    const int r0 = tr * 8;

    float acc[8][8];
#pragma unroll
    for (int r = 0; r < 8; r++)
#pragma unroll
        for (int c = 0; c < 8; c++) acc[r][c] = 0.f;

    const int rr = t >> 3;
    const int kk = (t & 7) * 4;
    const int kw = t >> 3;
    const int cw = (t & 7) * 16;

    for (int k0 = 0; k0 < Dd; k0 += KC) {
#pragma unroll
        for (int i = 0; i < 4; i++) {
            const float4 xv = *(const float4*)(X + (size_t)(m0 + rr + 32 * i) * Dd + k0 + kk);
            Xs[kk + 0][rr + 32 * i] = xv.x;
            Xs[kk + 1][rr + 32 * i] = xv.y;
            Xs[kk + 2][rr + 32 * i] = xv.z;
            Xs[kk + 3][rr + 32 * i] = xv.w;
        }
        {
            const float4* src = (const float4*)(Wp + (size_t)(k0 + kw) * NC + cw);
#pragma unroll
            for (int i = 0; i < 4; i++) {
                *(float4*)&Ws[kw][cw + 4 * i] = src[i];
            }
        }
        __syncthreads();
#pragma unroll 8
        for (int k = 0; k < KC; k++) {
            float4 x0 = *(const float4*)&Xs[k][r0];
            float4 x1 = *(const float4*)&Xs[k][r0 + 4];
            float4 w0 = *(const float4*)&Ws[k][c0];
            float4 w1 = *(const float4*)&Ws[k][c0 + 4];
            float xr[8] = {x0.x, x0.y, x0.z, x0.w, x1.x, x1.y, x1.z, x1.w};
            float wc[8] = {w0.x, w0.y, w0.z, w0.w, w1.x, w1.y, w1.z, w1.w};
#pragma unroll
            for (int r = 0; r < 8; r++)
#pragma unroll
                for (int c = 0; c < 8; c++)
                    acc[r][c] = fmaf(xr[r], wc[c], acc[r][c]);
        }
        __syncthreads();
    }

    float biasv[8];
#pragma unroll
    for (int c = 0; c < 8; c++) {
        int cc = c0 + c;
        biasv[c] = (cc < 120) ? (bih[cc] + bhh[cc])
                 : (cc == 120) ? ba[0]
                 : (cc == 121) ? bbp[0] : 0.f;
    }
#pragma unroll
    for (int r = 0; r < 8; r++) {
        float4 o0, o1;
        o0.x = acc[r][0] + biasv[0]; o0.y = acc[r][1] + biasv[1];
        o0.z = acc[r][2] + biasv[2]; o0.w = acc[r][3] + biasv[3];
        o1.x = acc[r][4] + biasv[4]; o1.y = acc[r][5] + biasv[5];
        o1.z = acc[r][6] + biasv[6]; o1.w = acc[r][7] + biasv[7];
        float* dst = GX + (size_t)(m0 + r0 + r) * NC + c0;
        *(float4*)(dst + 0) = o0;
        *(float4*)(dst + 4) = o1;
    }
}

// ---------------- kernel 3: sequential scan, one wave per batch row ----------------
__global__ __launch_bounds__(64) void scan_k(const float* __restrict__ u,
                                             const float* __restrict__ gx,
                                             const float* __restrict__ Whh,
                                             const float* __restrict__ Wih,
                                             const float* __restrict__ Wa,
                                             const float* __restrict__ Wb,
                                             float* __restrict__ out) {
    __shared__ float us[Tt];
    const int b = blockIdx.x;
    const int l = threadIdx.x;

    for (int k = l; k < Tt; k += 64) us[k] = u[b * Tt + k];
    __syncthreads();

    int rowA = -1, rowB = -1;
    if (l < 30)                 { rowA = l;      rowB = 30 + l; }
    else if (l >= 32 && l < 62) { rowA = l + 28; rowB = l + 58; }

    float wA[Hh], wB[Hh];
#pragma unroll
    for (int k = 0; k < Hh; k++) { wA[k] = 0.f; wB[k] = 0.f; }
    float wzA = 0.f, wzB = 0.f;
    if (rowA >= 0) {
        for (int k = 0; k < Hh; k++) { wA[k] = Whh[rowA * Hh + k]; wB[k] = Whh[rowB * Hh + k]; }
        wzA = Wih[rowA * (Dd + 1) + Dd];
        wzB = Wih[rowB * (Dd + 1) + Dd];
    } else if (l == 30) {
        for (int k = 0; k < Hh; k++) wA[k] = Wa[Dd + k];
    } else if (l == 31) {
        for (int k = 0; k < Hh; k++) wA[k] = Wb[Dd + k];
    }
    const int cA = (rowA >= 0) ? rowA : ((l == 30) ? 120 : ((l == 31) ? 121 : 126));
    const int cB = (rowB >= 0) ? rowB : 127;
    const float* gxb = gx + (size_t)b * Tt * NC;

    float h[Hh];
#pragma unroll
    for (int k = 0; k < Hh; k++) h[k] = 0.f;
    float cst = 0.f;

    float gA = gxb[cA];
    float gB = gxb[cB];

    for (int t = 0; t < Tt; t++) {
        float accA = gA, accB = gB;
#pragma unroll
        for (int k = 0; k < Hh; k++) {
            accA = fmaf(wA[k], h[k], accA);
            accB = fmaf(wB[k], h[k], accB);
        }
        if (t + 1 < Tt) {
            gA = gxb[(size_t)(t + 1) * NC + cA];
            gB = gxb[(size_t)(t + 1) * NC + cB];
        }
        const float av = rl_f(accA, 30);
        const float bv = rl_f(accA, 31);
        float a = fminf(fmaxf(softplus_(av), 1e-6f), 100.f);
        float bk = fminf(fmaxf(softplus_(bv), 1e-6f), 100.f);
        float uu = us[t];
        uu = fminf(fmaxf(uu, 1e-5f), 1.f - 1e-5f);
        float p = __expf(__logf(1.f - uu) / bk);
        float inner = 1.f - p;
        float s = (inner <= 0.f) ? 0.f : __expf(__logf(inner) / a);
        float z = fminf(fmaxf(fmaf(1.2f, s, -0.1f), 0.f), 1.f);
        accA = fmaf(z, wzA, accA);
        accB = fmaf(z, wzB, accB);
        const int srcb = ((l & 31) + 32) << 2;
        const float gg = __uint_as_float(__builtin_amdgcn_ds_bpermute(srcb, __float_as_uint(accA)));
        const float oo = __uint_as_float(__builtin_amdgcn_ds_bpermute(srcb, __float_as_uint(accB)));
        const float iv = sigmoidf_(accA);
        const float fv = sigmoidf_(accB);
        const float cn = fv * cst + iv * tanhf_fast(gg);
        const float hn = sigmoidf_(oo) * tanhf_fast(cn);
        cst = cn;
#pragma unroll
        for (int k = 0; k < Hh; k++) h[k] = rl_f(hn, k);
        if (l == 0) out[b * Tt + t] = z;
    }
}

extern "C" void kernel_launch(void* const* d_in, const int* in_sizes, int n_in,
                              void* d_out, int out_size, void* d_ws, size_t ws_size,
                              hipStream_t stream) {
    const float* x   = (const float*)d_in[0];
    const float* u   = (const float*)d_in[1];
    const float* Wih = (const float*)d_in[2];
    const float* Whh = (const float*)d_in[3];
    const float* bih = (const float*)d_in[4];
    const float* bhh = (const float*)d_in[5];
    const float* Wa  = (const float*)d_in[6];
    const float* ba  = (const float*)d_in[7];
    const float* Wb  = (const float*)d_in[8];
    const float* bbp = (const float*)d_in[9];
    float* out = (float*)d_out;

    float* Wp = (float*)d_ws;                 // [1536][128]  = 786,432 B
    float* GX = Wp + (size_t)Dd * NC;         // [32768][128] = 16,777,216 B

    pack_w<<<(Dd * NC) / 256, 256, 0, stream>>>(Wih, Wa, Wb, Wp);
    gemm_k<<<Mm / 128, 256, 0, stream>>>(x, Wp, bih, bhh, ba, bbp, GX);
    scan_k<<<Bb, 64, 0, stream>>>(u, GX, Whh, Wih, Wa, Wb, out);
}